// Round 10
// baseline (376.860 us; speedup 1.0000x reference)
//
#include <hip/hip_runtime.h>
#include <math.h>

// Problem constants (from reference)
#define HH 256
#define WW 256
#define CC 32
#define SS 32
#define NRAYS 32768            // N*R = 2*16384
#define RPB 8                  // rays per block
#define TEXOFF 256             // byte offset of HWC bf16 texture in d_ws
#define TEXBYTES ((size_t)6 * HH * WW * CC * 2)

// LDS pool layout (bytes, all 16-aligned)
#define FXB_OFF 0              // 256 rows x 80 B (32 bf16 ch in bytes [0,64))
#define SIG_OFF 20480          // f32[256] raw sigma (post-gather)
#define WST_OFF 21504          // w1t 4096 B | w2t 6144 B; dies after fragment preload
#define W2T_OFF 25600
#define ALP_OFF 31744          // f32[256] alpha->weights (post-gather)
#define POOLSZ  32768          // 32 KB x 4 blocks x 512 thr = 2048 thr/CU (100% occ)
#define RECB_OFF 20480         // during gather: 256 x 48 B bilinear records
// NOTE: no __syncthreads_or anywhere — it allocates a hidden 512 B LDS scratch
// (measured r4: LDS 32768->33280, occupancy -25%).

typedef __attribute__((ext_vector_type(8))) short short8;   // 8 bf16
typedef __attribute__((ext_vector_type(4))) float f32x4;
typedef __attribute__((ext_vector_type(2))) float f32x2;

__device__ __forceinline__ f32x4 mfma16(short8 a, short8 b, f32x4 c) {
    return __builtin_amdgcn_mfma_f32_16x16x32_bf16(a, b, c, 0, 0, 0);
}

// ---------- helpers ----------
__device__ __forceinline__ float bf2f(unsigned short u) {
    union { unsigned int ui; float f; } v; v.ui = ((unsigned int)u) << 16; return v.f;
}
__device__ __forceinline__ float lo2f(unsigned int w) {
    union { unsigned int ui; float f; } v; v.ui = w << 16; return v.f;
}
__device__ __forceinline__ float hi2f(unsigned int w) {
    union { unsigned int ui; float f; } v; v.ui = w & 0xffff0000u; return v.f;
}
// HW packed f32->bf16 (RNE, 1 instr for 2 values)
__device__ __forceinline__ unsigned int cvtpk2(float a, float b) {
    unsigned int r;
    asm("v_cvt_pk_bf16_f32 %0, %1, %2" : "=v"(r) : "v"(a), "v"(b));
    return r;
}
__device__ __forceinline__ unsigned short f2bf_cvt(float f) {
    unsigned int r;
    asm("v_cvt_pk_bf16_f32 %0, %1, %2" : "=v"(r) : "v"(f), "v"(f));
    return (unsigned short)r;
}
// packed 2xf32 math (CDNA4 v_pk_*_f32; IEEE per half — bit-identical to scalar)
__device__ __forceinline__ f32x2 pk_mul(f32x2 a, f32x2 b) {
    f32x2 d; asm("v_pk_mul_f32 %0, %1, %2" : "=v"(d) : "v"(a), "v"(b)); return d;
}
__device__ __forceinline__ f32x2 pk_fma(f32x2 a, f32x2 b, f32x2 c) {
    f32x2 d; asm("v_pk_fma_f32 %0, %1, %2, %3" : "=v"(d) : "v"(a), "v"(b), "v"(c)); return d;
}
__device__ __forceinline__ f32x2 pk_add(f32x2 a, f32x2 b) {
    f32x2 d; asm("v_pk_add_f32 %0, %1, %2" : "=v"(d) : "v"(a), "v"(b)); return d;
}
__device__ __forceinline__ f32x2 unpk2(unsigned int w) {   // (lo bf16, hi bf16) -> 2xf32
    f32x2 d; d.x = lo2f(w); d.y = hi2f(w); return d;
}
__device__ __forceinline__ int iclamp(int x, int lo, int hi) {
    return x < lo ? lo : (x > hi ? hi : x);
}
__device__ __forceinline__ float softplus_f(float z) {       // precise (fallback)
    return fmaxf(z, 0.f) + log1pf(expf(-fabsf(z)));
}
__device__ __forceinline__ float softplus_fast(float z) {
    return fmaxf(z, 0.f) + __logf(1.0f + __expf(-fabsf(z)));
}
__device__ __forceinline__ float sigmoid_fast(float z) {
    return __builtin_amdgcn_rcpf(1.0f + __expf(-z));
}

template<bool F32>
__device__ __forceinline__ float ldv(const void* p, size_t i) {
    if (F32) return ((const float*)p)[i];
    else     return bf2f(((const unsigned short*)p)[i]);
}

// ---------- dtype detection (in-kernel): |ray_origin| == 2.7 by construction ----------
__device__ __forceinline__ int detect_f32_local(const void* __restrict__ rayo) {
    const float* f = (const float*)rayo;
    const unsigned short* u = (const unsigned short*)rayo;
    float sf = 0.f, sb = 0.f;
    #pragma unroll
    for (int i = 0; i < 8; ++i) {
        const float a = f[3 * i], b = f[3 * i + 1], c = f[3 * i + 2];
        const float nf = a * a + b * b + c * c;
        sf += fminf(fabsf(nf - 7.29f), 1e3f);            // fminf(NaN,x)=x -> NaN-safe
        const float x = bf2f(u[3 * i]), y = bf2f(u[3 * i + 1]), z = bf2f(u[3 * i + 2]);
        const float nb = x * x + y * y + z * z;
        sb += fminf(fabsf(nb - 7.29f), 1e3f);
    }
    return (sf < sb) ? 1 : 0;
}

// ---------- CHW -> HWC transpose; OUTPUT ALWAYS bf16 (r8 shape, verified r9) ----------
__global__ __launch_bounds__(256) void transpose_tex(
    const void* __restrict__ vol, unsigned short* __restrict__ tex,
    const void* __restrict__ rayo) {
    __shared__ __align__(16) unsigned short tb[32][36];   // 72 B rows: ~2-way banks
    __shared__ int sflag;
    const int l = threadIdx.x;
    if (l == 0) sflag = detect_f32_local(rayo);
    const int tx = l & 7, ty = l >> 3;     // phase 1: c = ty (0..31), w-quad = tx (0..7)
    const int wq = l >> 3, cq = l & 7;     // phase 2: w = w0+wq (0..31), c-quad = cq
    const int w0 = (blockIdx.x & 7) * 32;
    const int h  = blockIdx.x >> 3;
    const int img = blockIdx.y;
    const size_t srcE = (((size_t)img * CC + ty) * HH + h) * WW + w0 + 4 * tx;
    const size_t dstE = (((size_t)img * HH + h) * WW + (w0 + wq)) * CC + 4 * cq;
    __syncthreads();
    if (sflag) {
        const float4 v = *(const float4*)((const float*)vol + srcE);
        tb[ty][4 * tx + 0] = f2bf_cvt(v.x); tb[ty][4 * tx + 1] = f2bf_cvt(v.y);
        tb[ty][4 * tx + 2] = f2bf_cvt(v.z); tb[ty][4 * tx + 3] = f2bf_cvt(v.w);
    } else {
        *(ushort4*)&tb[ty][4 * tx] = *(const ushort4*)((const unsigned short*)vol + srcE);
    }
    __syncthreads();
    ushort4 o;
    o.x = tb[4 * cq + 0][wq]; o.y = tb[4 * cq + 1][wq];
    o.z = tb[4 * cq + 2][wq]; o.w = tb[4 * cq + 3][wq];
    *(ushort4*)(tex + dstE) = o;
}

// ================= fast path: bf16 gather + MFMA MLP + split marcher =================
// r10: 512 threads/block, 8 waves. Gather = 1 wave/ray (2 samples/lane).
// MLP on waves 0..3 (hb fits 4x2304 B in WST region); marcher on t<256.
template<bool F32>
__device__ void render_mfma_body(
    const unsigned short* __restrict__ tex,   // [6][256][256][32] bf16 HWC
    const void* __restrict__ rayo, const void* __restrict__ rayd,
    const void* __restrict__ w1b, const void* __restrict__ b1b,
    const void* __restrict__ w2b, const void* __restrict__ b2b,
    void* __restrict__ outp, char* __restrict__ pool)
{
    const int t = threadIdx.x;
    unsigned short* fxB = (unsigned short*)(pool + FXB_OFF);   // stride 40 ushort/row
    float* sigL = (float*)(pool + SIG_OFF);
    unsigned short* w1t = (unsigned short*)(pool + WST_OFF);   // [n<64][k<32]
    unsigned short* w2t = (unsigned short*)(pool + W2T_OFF);   // [n<48][k<64]
    float* aL = (float*)(pool + ALP_OFF);                      // alpha -> weights

    // ---- stage weights: LINEAR LDS writes; transpose in the global read index ----
    for (int i = t; i < 2048; i += 512) {        // w1t[i], layout [n][k] stride 32
        const int n = i >> 5, k = i & 31;
        w1t[i] = f2bf_cvt(ldv<F32>(w1b, (size_t)k * 64 + n));
    }
    for (int i = t; i < 3072; i += 512) {        // w2t[i], layout [n][k] stride 64
        const int n = i >> 6, k = i & 63;
        w2t[i] = (n < 33) ? f2bf_cvt(ldv<F32>(w2b, (size_t)k * 33 + n)) : (unsigned short)0;
    }
    __syncthreads();

    // ---- B fragments to registers NOW (records will overwrite w1t/w2t) ----
    // Only MLP waves (w < 4) need them.
    const int w = t >> 6;
    const int lane = t & 63;
    const int l16 = lane & 15, quad = lane >> 4;

    short8 b1f[4];
    short8 b2f[3][2];
    float bb1[4], bb2[3];
    if (w < 4) {
        #pragma unroll
        for (int nt = 0; nt < 4; nt++)
            b1f[nt] = *(const short8*)(pool + WST_OFF + (nt * 16 + l16) * 64 + quad * 16);
        #pragma unroll
        for (int nt = 0; nt < 3; nt++)
            #pragma unroll
            for (int ks = 0; ks < 2; ks++)
                b2f[nt][ks] = *(const short8*)(pool + W2T_OFF + (nt * 16 + l16) * 128 + ks * 64 + quad * 16);
        #pragma unroll
        for (int nt = 0; nt < 4; nt++) bb1[nt] = ldv<F32>(b1b, nt * 16 + l16);
        #pragma unroll
        for (int nt = 0; nt < 3; nt++) {
            const int n2 = nt * 16 + l16;
            bb2[nt] = (n2 < 33) ? ldv<F32>(b2b, n2) : 0.f;
        }
    }
    __syncthreads();   // all w1t/w2t reads done before records overwrite

    // ---- record precompute: thread t<256 = sample row t; weights/indices ONCE ----
    // writer row t: ray rl_w = t>>5, sample s_w = t&31.
    // ji = (s_w>>1) | ((s_w&1)<<4) | (rl_w<<5): reader's 16 concurrent records
    // (fixed k) are ji-consecutive -> 48 B stride -> 2-way banks max + broadcast.
    if (t < 256) {
        const int s = t & 31;
        const int gray = blockIdx.x * RPB + (t >> 5);
        const size_t rb = (size_t)gray * 3;
        const float ox = ldv<F32>(rayo, rb), oy = ldv<F32>(rayo, rb + 1), oz = ldv<F32>(rayo, rb + 2);
        const float dx = ldv<F32>(rayd, rb), dy = ldv<F32>(rayd, rb + 1), dz = ldv<F32>(rayd, rb + 2);
        const float d = 2.25f + 1.05f * ((s + 0.5f) * (1.0f / 32.0f));
        const float x = (ox + d * dx) * 2.0f;
        const float y = (oy + d * dy) * 2.0f;
        const float z = (oz + d * dz) * 2.0f;
        const int ji = ((s >> 1) & 15) | ((s & 1) << 4) | (t & 224);
        char* recp = pool + RECB_OFF + ji * 48;
        #pragma unroll
        for (int p = 0; p < 3; p++) {
            // p0:(x,y)  p1:(y,z)  p2:(x,z)
            const float u = (p == 0) ? x : ((p == 1) ? y : x);
            const float v = (p == 0) ? y : z;
            const float ixf = fmaf(u, 127.5f, 127.5f);
            const float iyf = fmaf(v, 127.5f, 127.5f);
            const float ix0f = floorf(ixf), iy0f = floorf(iyf);
            const float wx1 = ixf - ix0f, wy1 = iyf - iy0f;   // identical to round-0 math
            const int ix0 = iclamp((int)ix0f, 0, 255);
            const int ix1 = iclamp((int)ix0f + 1, 0, 255);
            const int iy0 = iclamp((int)iy0f, 0, 255);
            const int iy1 = iclamp((int)iy0f + 1, 0, 255);
            uint4 rec;
            rec.x = __float_as_uint(wx1);
            rec.y = __float_as_uint(wy1);
            rec.z = (unsigned int)(iy0 * WW + ix0) | ((unsigned int)(iy0 * WW + ix1) << 16);
            rec.w = (unsigned int)(iy1 * WW + ix0) | ((unsigned int)(iy1 * WW + ix1) << 16);
            *(uint4*)(recp + p * 16) = rec;
        }
    }
    __syncthreads();

    // ---- gather: ONE WAVE PER RAY; lane = (channel oct c4, sample subset sub);
    //      2 samples/lane; one dwordx4 per corner (4 lanes cover 64-B texel line) ----
    {
        const int rl = t >> 6;                 // ray in block = wave id
        const int L  = t & 63;
        const int c4 = L & 3;                  // channel oct: ch 8*c4..8*c4+7
        const int sub = L >> 2;                // sample subset 0..15 (2 samples)
        const int gray = blockIdx.x * RPB + rl;
        const int n = gray >> 14;
        const char* texb = (const char*)tex;
        const unsigned int cb = (unsigned int)c4 * 16;  // byte offset of channel oct
        unsigned int pbase[3];
        #pragma unroll
        for (int p = 0; p < 3; p++)
            pbase[p] = (unsigned int)(n * 3 + p) * (HH * WW * CC * 2) + cb;
        const char* recb = pool + RECB_OFF + (sub + (rl << 5)) * 48;

        #pragma unroll 1
        for (int k = 0; k < 2; ++k) {
            const int s = sub * 2 + k;
            const char* recp = recb + (k << 4) * 48;   // ji = sub | (k<<4) | (rl<<5)
            f32x2 a[3][4];                         // [plane][word] = 2 channels
            #pragma unroll
            for (int p = 0; p < 3; p++) {
                const uint4 rc = *(const uint4*)(recp + p * 16);
                const float wx1 = __uint_as_float(rc.x);
                const float wy1 = __uint_as_float(rc.y);
                const float wx0 = 1.f - wx1,  wy0 = 1.f - wy1;
                const float w00 = wx0 * wy0, w01 = wx1 * wy0, w10 = wx0 * wy1, w11 = wx1 * wy1;
                const f32x2 w00p = {w00, w00}, w01p = {w01, w01};
                const f32x2 w10p = {w10, w10}, w11p = {w11, w11};
                const unsigned int pb = pbase[p];
                const uint4 q00 = *(const uint4*)(texb + (pb + ((rc.z & 0xffffu) << 6)));
                const uint4 q01 = *(const uint4*)(texb + (pb + ((rc.z >> 16) << 6)));
                const uint4 q10 = *(const uint4*)(texb + (pb + ((rc.w & 0xffffu) << 6)));
                const uint4 q11 = *(const uint4*)(texb + (pb + ((rc.w >> 16) << 6)));
                const unsigned int* u00 = (const unsigned int*)&q00;
                const unsigned int* u01 = (const unsigned int*)&q01;
                const unsigned int* u10 = (const unsigned int*)&q10;
                const unsigned int* u11 = (const unsigned int*)&q11;
                #pragma unroll
                for (int i = 0; i < 4; i++) {      // word i = channels (2i, 2i+1)
                    f32x2 acc = pk_mul(w00p, unpk2(u00[i]));   // same order as scalar:
                    acc = pk_fma(w01p, unpk2(u01[i]), acc);    // w00*v00 +w01 +w10 +w11
                    acc = pk_fma(w10p, unpk2(u10[i]), acc);
                    acc = pk_fma(w11p, unpk2(u11[i]), acc);
                    a[p][i] = acc;
                }
            }
            // plane average ((a0+a1)+a2)*(1/3) packed, then 8 ch -> one b128 write
            const f32x2 third = {1.0f / 3.0f, 1.0f / 3.0f};
            uint4 pk;
            f32x2 s0 = pk_mul(pk_add(pk_add(a[0][0], a[1][0]), a[2][0]), third);
            f32x2 s1 = pk_mul(pk_add(pk_add(a[0][1], a[1][1]), a[2][1]), third);
            f32x2 s2 = pk_mul(pk_add(pk_add(a[0][2], a[1][2]), a[2][2]), third);
            f32x2 s3 = pk_mul(pk_add(pk_add(a[0][3], a[1][3]), a[2][3]), third);
            pk.x = cvtpk2(s0.x, s0.y);
            pk.y = cvtpk2(s1.x, s1.y);
            pk.z = cvtpk2(s2.x, s2.y);
            pk.w = cvtpk2(s3.x, s3.y);
            *(uint4*)(pool + FXB_OFF + (rl * 32 + s) * 80 + c4 * 16) = pk;
        }
    }
    __syncthreads();   // fxB ready; records dead (SIG/hb/ALP writers start below)

    // ---- MFMA MLP: waves 0..3, wave w owns sample rows [64w, 64w+64) ----
    if (w < 4) {
        char* hb = pool + WST_OFF + w * 2304;    // 16 rows x 144 B
        #pragma unroll 1
        for (int mt = 0; mt < 4; mt++) {
            const int rbase = w * 64 + mt * 16;
            const short8 a1 = *(const short8*)(pool + FXB_OFF + (rbase + l16) * 80 + quad * 16);
            #pragma unroll
            for (int nt = 0; nt < 4; nt++) {
                f32x4 hc = { bb1[nt], bb1[nt], bb1[nt], bb1[nt] };
                hc = mfma16(a1, b1f[nt], hc);
                #pragma unroll
                for (int r = 0; r < 4; r++) {
                    const float hv = softplus_fast(hc[r]);
                    *(unsigned short*)(hb + (quad * 4 + r) * 144 + (nt * 16 + l16) * 2) = f2bf_cvt(hv);
                }
            }
            const short8 a2k0 = *(const short8*)(hb + l16 * 144 + quad * 16);
            const short8 a2k1 = *(const short8*)(hb + l16 * 144 + 64 + quad * 16);
            #pragma unroll
            for (int nt = 0; nt < 3; nt++) {
                f32x4 o = { bb2[nt], bb2[nt], bb2[nt], bb2[nt] };
                o = mfma16(a2k0, b2f[nt][0], o);
                o = mfma16(a2k1, b2f[nt][1], o);
                #pragma unroll
                for (int r = 0; r < 4; r++) {
                    const int row = rbase + quad * 4 + r;
                    if (nt == 0) {
                        if (l16 == 0) sigL[row] = o[r];                      // raw sigma (n=0)
                        else fxB[row * 40 + (l16 - 1)] =
                                 f2bf_cvt(fmaf(sigmoid_fast(o[r]), 1.002f, -0.001f));   // ch 0..14
                    } else if (nt == 1) {
                        fxB[row * 40 + (15 + l16)] =
                                 f2bf_cvt(fmaf(sigmoid_fast(o[r]), 1.002f, -0.001f));   // ch 15..30
                    } else if (l16 == 0) {
                        fxB[row * 40 + 31] =
                                 f2bf_cvt(fmaf(sigmoid_fast(o[r]), 1.002f, -0.001f));   // ch 31
                    }
                }
            }
        }
    }
    __syncthreads();

    // ---- marcher phase 1: thread t<256 = (ray rl, interval sm) computes alpha ----
    if (t < 256) {
        const int rl = t >> 5, sm = t & 31;
        if (sm < 31) {
            const float sp = sigL[rl * 32 + sm];
            const float sn = sigL[rl * 32 + sm + 1];
            const float m = 0.5f * (sp + sn) - 1.0f;
            const float dens = fmaxf(m, 0.f) + __logf(1.0f + __expf(-fabsf(m)));
            aL[rl * 32 + sm] = 1.0f - __expf(-(1.05f / 32.0f) * dens);
        }
    }
    __syncthreads();

    // ---- marcher phase 2: one lane per ray does the serial T-scan -> 0.5*alpha*T ----
    if (t < 256) {
        const int rl = t >> 5, sm = t & 31;
        if (sm == 0) {
            float T = 1.0f;
            #pragma unroll
            for (int j = 0; j < 31; j++) {
                const float a = aL[rl * 32 + j];
                aL[rl * 32 + j] = (a * T) * 0.5f;
                T *= (1.0f - a + 1e-10f);
            }
        }
    }
    __syncthreads();

    // ---- marcher phase 3: pure FMA channel walk ----
    if (t < 256) {
        const int rl = t >> 5, c = t & 31;
        const int gr2 = blockIdx.x * RPB + rl;
        float acc = 0.0f;
        float rp = bf2f(fxB[(rl * 32 + 0) * 40 + c]);
        #pragma unroll 4
        for (int sm = 0; sm < 31; sm++) {
            const float rn = bf2f(fxB[(rl * 32 + sm + 1) * 40 + c]);
            acc = fmaf(aL[rl * 32 + sm], rp + rn, acc);
            rp = rn;
        }
        const size_t oidx = (size_t)gr2 * 32 + c;
        if (F32) ((float*)outp)[oidx] = acc;
        else     ((unsigned short*)outp)[oidx] = f2bf_cvt(acc);
    }
}

__global__ __launch_bounds__(512, 8) void render_fast(
    const unsigned short* __restrict__ tex, const void* __restrict__ rayo,
    const void* __restrict__ rayd, const void* __restrict__ w1b,
    const void* __restrict__ b1b, const void* __restrict__ w2b,
    const void* __restrict__ b2b, void* __restrict__ outp)
{
    __shared__ __align__(16) char pool[POOLSZ];
    const int t = threadIdx.x;
    if (t == 0) *(int*)pool = detect_f32_local(rayo);   // FXB space: dead until gather
    __syncthreads();
    const int f32flag = *(const int*)pool;   // every thread reads BEFORE staging barrier
    if (f32flag) render_mfma_body<true >(tex, rayo, rayd, w1b, b1b, w2b, b2b, outp, pool);
    else         render_mfma_body<false>(tex, rayo, rayd, w1b, b1b, w2b, b2b, outp, pool);
}

// ================= no-workspace fallback (round-3 verified) =================
template<bool F32>
__device__ __forceinline__ void render_body(
    const void* __restrict__ vol, const void* __restrict__ rayo,
    const void* __restrict__ rayd, const void* __restrict__ w1b,
    const void* __restrict__ b1b, const void* __restrict__ w2b,
    const void* __restrict__ b2b, void* __restrict__ outp,
    float* wsm, float (*rgbL)[SS][33], float (*sigL)[SS])
{
    const int t = threadIdx.x;
    for (int i = t; i < 4257; i += 256) {
        float v;
        if (i < 2048)       v = ldv<F32>(w1b, i);
        else if (i < 2112)  v = ldv<F32>(b1b, i - 2048);
        else if (i < 4224)  v = ldv<F32>(w2b, i - 2112);
        else                v = ldv<F32>(b2b, i - 4224);
        wsm[i] = v;
    }
    __syncthreads();

    const int rl = t >> 5;
    const int s  = t & 31;
    const int gray = blockIdx.x * RPB + rl;
    const int n = gray >> 14;

    const size_t rbase = (size_t)gray * 3;
    const float ox = ldv<F32>(rayo, rbase), oy = ldv<F32>(rayo, rbase + 1), oz = ldv<F32>(rayo, rbase + 2);
    const float dx = ldv<F32>(rayd, rbase), dy = ldv<F32>(rayd, rbase + 1), dz = ldv<F32>(rayd, rbase + 2);
    const float d = 2.25f + 1.05f * ((s + 0.5f) * (1.0f / 32.0f));
    const float x = (ox + d * dx) * 2.0f;
    const float y = (oy + d * dy) * 2.0f;
    const float z = (oz + d * dz) * 2.0f;

    float fx[32];
    #pragma unroll
    for (int c = 0; c < 32; c++) fx[c] = 0.f;

    #pragma unroll
    for (int p = 0; p < 3; p++) {
        const float u = (p == 0) ? x : ((p == 1) ? y : x);
        const float v = (p == 0) ? y : z;
        const float ixf = fmaf(u, 127.5f, 127.5f);
        const float iyf = fmaf(v, 127.5f, 127.5f);
        const float ix0f = floorf(ixf), iy0f = floorf(iyf);
        const float wx1 = ixf - ix0f, wy1 = iyf - iy0f;
        const float wx0 = 1.f - wx1,  wy0 = 1.f - wy1;
        const int ix0 = iclamp((int)ix0f, 0, 255);
        const int ix1 = iclamp((int)ix0f + 1, 0, 255);
        const int iy0 = iclamp((int)iy0f, 0, 255);
        const int iy1 = iclamp((int)iy0f + 1, 0, 255);
        const float wnw = wx0 * wy0, wne = wx1 * wy0, wsw = wx0 * wy1, wse = wx1 * wy1;
        const int i00 = iy0 * WW + ix0, i01 = iy0 * WW + ix1;
        const int i10 = iy1 * WW + ix0, i11 = iy1 * WW + ix1;
        const size_t pb = (size_t)(n * 3 + p) * CC * HH * WW;
        #pragma unroll
        for (int c = 0; c < 32; c++) {
            const size_t cb = pb + (size_t)c * (HH * WW);
            fx[c] += wnw * ldv<F32>(vol, cb + i00) + wne * ldv<F32>(vol, cb + i01)
                   + wsw * ldv<F32>(vol, cb + i10) + wse * ldv<F32>(vol, cb + i11);
        }
    }
    #pragma unroll
    for (int c = 0; c < 32; c++) fx[c] *= (1.0f / 3.0f);

    const float* W1 = wsm;
    const float* B1 = wsm + 2048;
    const float* W2 = wsm + 2112;
    const float* B2 = wsm + 4224;

    float h[64];
    #pragma unroll
    for (int j = 0; j < 64; j++) h[j] = B1[j];
    #pragma unroll
    for (int c = 0; c < 32; c++) {
        const float f = fx[c];
        #pragma unroll
        for (int j = 0; j < 64; j++) h[j] = fmaf(f, W1[c * 64 + j], h[j]);
    }
    #pragma unroll
    for (int j = 0; j < 64; j++) h[j] = softplus_f(h[j]);

    #pragma unroll 1
    for (int k = 0; k < 33; k++) {
        float zz = B2[k];
        #pragma unroll
        for (int j = 0; j < 64; j++) zz = fmaf(h[j], W2[j * 33 + k], zz);
        if (k == 0) sigL[rl][s] = zz;
        else {
            const float sg = 1.0f / (1.0f + expf(-zz));
            rgbL[rl][s][k - 1] = fmaf(sg, 1.002f, -0.001f);
        }
    }
    __syncthreads();

    const int c = t & 31;
    const float delta = 1.05f / 32.0f;
    float T = 1.0f, acc = 0.0f;
    float sig_prev = sigL[rl][0];
    float rgb_prev = rgbL[rl][0][c];
    #pragma unroll 1
    for (int sm = 0; sm < 31; sm++) {
        const float sig_next = sigL[rl][sm + 1];
        const float rgb_next = rgbL[rl][sm + 1][c];
        const float dens = softplus_f(0.5f * (sig_prev + sig_next) - 1.0f);
        const float alpha = 1.0f - expf(-delta * dens);
        acc += alpha * T * 0.5f * (rgb_prev + rgb_next);
        T *= (1.0f - alpha + 1e-10f);
        sig_prev = sig_next;
        rgb_prev = rgb_next;
    }
    const size_t oidx = (size_t)gray * 32 + c;
    if (F32) ((float*)outp)[oidx] = acc;
    else     ((unsigned short*)outp)[oidx] = f2bf_cvt(acc);
}

__global__ __launch_bounds__(256) void render_any(
    const void* __restrict__ vol, const void* __restrict__ rayo,
    const void* __restrict__ rayd, const void* __restrict__ w1b,
    const void* __restrict__ b1b, const void* __restrict__ w2b,
    const void* __restrict__ b2b, void* __restrict__ outp)
{
    __shared__ float wsm[4257];
    __shared__ float rgbL[RPB][SS][33];
    __shared__ float sigL[RPB][SS];
    __shared__ int sflag;
    if (threadIdx.x == 0) sflag = detect_f32_local(rayo);
    __syncthreads();
    const int f32flag = sflag;
    __syncthreads();
    if (f32flag) render_body<true >(vol, rayo, rayd, w1b, b1b, w2b, b2b, outp, wsm, rgbL, sigL);
    else         render_body<false>(vol, rayo, rayd, w1b, b1b, w2b, b2b, outp, wsm, rgbL, sigL);
}

extern "C" void kernel_launch(void* const* d_in, const int* in_sizes, int n_in,
                              void* d_out, int out_size, void* d_ws, size_t ws_size,
                              hipStream_t stream) {
    const void* vol  = d_in[0];
    const void* rayo = d_in[1];
    const void* rayd = d_in[2];
    const void* w1   = d_in[3];
    const void* b1   = d_in[4];
    const void* w2   = d_in[5];
    const void* b2   = d_in[6];
    unsigned short* tex = (unsigned short*)((char*)d_ws + TEXOFF);

    const size_t need = TEXOFF + TEXBYTES;   // bf16 texture always

    if (ws_size >= need) {
        transpose_tex<<<dim3(8 * HH, 6), dim3(256), 0, stream>>>(vol, tex, rayo);
        render_fast<<<dim3(NRAYS / RPB), dim3(512), 0, stream>>>(
            tex, rayo, rayd, w1, b1, w2, b2, d_out);
    } else {
        render_any<<<dim3(NRAYS / RPB), dim3(256), 0, stream>>>(
            vol, rayo, rayd, w1, b1, w2, b2, d_out);
    }
}

// Round 11
// 234.884 us; speedup vs baseline: 1.6045x; 1.6045x over previous
//
#include <hip/hip_runtime.h>
#include <math.h>

// Problem constants (from reference)
#define HH 256
#define WW 256
#define CC 32
#define SS 32
#define NRAYS 32768            // N*R = 2*16384
#define RPB 8                  // rays per block
#define TEXOFF 256             // byte offset of HWC bf16 texture in d_ws
#define TEXBYTES ((size_t)6 * HH * WW * CC * 2)

// LDS pool layout (bytes, all 16-aligned)
#define FXB_OFF 0              // 256 rows x 80 B (32 bf16 ch in bytes [0,64))
#define SIG_OFF 20480          // f32[256] raw sigma (post-gather)
#define WST_OFF 21504          // w1t 4096 B | w2t 6144 B; dies after fragment preload
#define W2T_OFF 25600
#define ALP_OFF 31744          // f32[256] alpha->weights (post-gather)
#define POOLSZ  32768          // 32 KB x 4 blocks x 512 thr = 2048 thr/CU (100% occ)
#define RECB_OFF 20480         // during gather: 256 x 48 B bilinear records
// NOTE: no __syncthreads_or anywhere — hidden 512 B LDS scratch (r4: occupancy -25%).
// NOTE r10: __launch_bounds__(512,8) forced VGPR=32 -> scratch spill (WRITE_SIZE
// 4->386 MB, render 130->296 us). Use (512,4): cap 128, compiler lands ~48-64,
// HW still schedules 4 blocks/CU when VGPR<=64.

typedef __attribute__((ext_vector_type(8))) short short8;   // 8 bf16
typedef __attribute__((ext_vector_type(4))) float f32x4;
typedef __attribute__((ext_vector_type(2))) float f32x2;

__device__ __forceinline__ f32x4 mfma16(short8 a, short8 b, f32x4 c) {
    return __builtin_amdgcn_mfma_f32_16x16x32_bf16(a, b, c, 0, 0, 0);
}

// ---------- helpers ----------
__device__ __forceinline__ float bf2f(unsigned short u) {
    union { unsigned int ui; float f; } v; v.ui = ((unsigned int)u) << 16; return v.f;
}
__device__ __forceinline__ float lo2f(unsigned int w) {
    union { unsigned int ui; float f; } v; v.ui = w << 16; return v.f;
}
__device__ __forceinline__ float hi2f(unsigned int w) {
    union { unsigned int ui; float f; } v; v.ui = w & 0xffff0000u; return v.f;
}
// HW packed f32->bf16 (RNE, 1 instr for 2 values)
__device__ __forceinline__ unsigned int cvtpk2(float a, float b) {
    unsigned int r;
    asm("v_cvt_pk_bf16_f32 %0, %1, %2" : "=v"(r) : "v"(a), "v"(b));
    return r;
}
__device__ __forceinline__ unsigned short f2bf_cvt(float f) {
    unsigned int r;
    asm("v_cvt_pk_bf16_f32 %0, %1, %2" : "=v"(r) : "v"(f), "v"(f));
    return (unsigned short)r;
}
// packed 2xf32 math (CDNA4 v_pk_*_f32; IEEE per half — bit-identical to scalar)
__device__ __forceinline__ f32x2 pk_mul(f32x2 a, f32x2 b) {
    f32x2 d; asm("v_pk_mul_f32 %0, %1, %2" : "=v"(d) : "v"(a), "v"(b)); return d;
}
__device__ __forceinline__ f32x2 pk_fma(f32x2 a, f32x2 b, f32x2 c) {
    f32x2 d; asm("v_pk_fma_f32 %0, %1, %2, %3" : "=v"(d) : "v"(a), "v"(b), "v"(c)); return d;
}
__device__ __forceinline__ f32x2 pk_add(f32x2 a, f32x2 b) {
    f32x2 d; asm("v_pk_add_f32 %0, %1, %2" : "=v"(d) : "v"(a), "v"(b)); return d;
}
__device__ __forceinline__ f32x2 unpk2(unsigned int w) {   // (lo bf16, hi bf16) -> 2xf32
    f32x2 d; d.x = lo2f(w); d.y = hi2f(w); return d;
}
__device__ __forceinline__ int iclamp(int x, int lo, int hi) {
    return x < lo ? lo : (x > hi ? hi : x);
}
__device__ __forceinline__ float softplus_f(float z) {       // precise (fallback)
    return fmaxf(z, 0.f) + log1pf(expf(-fabsf(z)));
}
__device__ __forceinline__ float softplus_fast(float z) {
    return fmaxf(z, 0.f) + __logf(1.0f + __expf(-fabsf(z)));
}
__device__ __forceinline__ float sigmoid_fast(float z) {
    return __builtin_amdgcn_rcpf(1.0f + __expf(-z));
}

template<bool F32>
__device__ __forceinline__ float ldv(const void* p, size_t i) {
    if (F32) return ((const float*)p)[i];
    else     return bf2f(((const unsigned short*)p)[i]);
}

// ---------- dtype detection (in-kernel): |ray_origin| == 2.7 by construction ----------
__device__ __forceinline__ int detect_f32_local(const void* __restrict__ rayo) {
    const float* f = (const float*)rayo;
    const unsigned short* u = (const unsigned short*)rayo;
    float sf = 0.f, sb = 0.f;
    #pragma unroll
    for (int i = 0; i < 8; ++i) {
        const float a = f[3 * i], b = f[3 * i + 1], c = f[3 * i + 2];
        const float nf = a * a + b * b + c * c;
        sf += fminf(fabsf(nf - 7.29f), 1e3f);            // fminf(NaN,x)=x -> NaN-safe
        const float x = bf2f(u[3 * i]), y = bf2f(u[3 * i + 1]), z = bf2f(u[3 * i + 2]);
        const float nb = x * x + y * y + z * z;
        sb += fminf(fabsf(nb - 7.29f), 1e3f);
    }
    return (sf < sb) ? 1 : 0;
}

// ---------- CHW -> HWC transpose; OUTPUT ALWAYS bf16 (r8 shape, verified r9) ----------
__global__ __launch_bounds__(256) void transpose_tex(
    const void* __restrict__ vol, unsigned short* __restrict__ tex,
    const void* __restrict__ rayo) {
    __shared__ __align__(16) unsigned short tb[32][36];   // 72 B rows: ~2-way banks
    __shared__ int sflag;
    const int l = threadIdx.x;
    if (l == 0) sflag = detect_f32_local(rayo);
    const int tx = l & 7, ty = l >> 3;     // phase 1: c = ty (0..31), w-quad = tx (0..7)
    const int wq = l >> 3, cq = l & 7;     // phase 2: w = w0+wq (0..31), c-quad = cq
    const int w0 = (blockIdx.x & 7) * 32;
    const int h  = blockIdx.x >> 3;
    const int img = blockIdx.y;
    const size_t srcE = (((size_t)img * CC + ty) * HH + h) * WW + w0 + 4 * tx;
    const size_t dstE = (((size_t)img * HH + h) * WW + (w0 + wq)) * CC + 4 * cq;
    __syncthreads();
    if (sflag) {
        const float4 v = *(const float4*)((const float*)vol + srcE);
        tb[ty][4 * tx + 0] = f2bf_cvt(v.x); tb[ty][4 * tx + 1] = f2bf_cvt(v.y);
        tb[ty][4 * tx + 2] = f2bf_cvt(v.z); tb[ty][4 * tx + 3] = f2bf_cvt(v.w);
    } else {
        *(ushort4*)&tb[ty][4 * tx] = *(const ushort4*)((const unsigned short*)vol + srcE);
    }
    __syncthreads();
    ushort4 o;
    o.x = tb[4 * cq + 0][wq]; o.y = tb[4 * cq + 1][wq];
    o.z = tb[4 * cq + 2][wq]; o.w = tb[4 * cq + 3][wq];
    *(ushort4*)(tex + dstE) = o;
}

// ================= fast path: bf16 gather + MFMA MLP + split marcher =================
// r10 structure: 512 threads/block, 8 waves. Gather = 1 wave/ray (2 samples/lane).
// MLP on waves 0..3 (hb fits 4x2304 B in WST region); marcher on t<256.
template<bool F32>
__device__ void render_mfma_body(
    const unsigned short* __restrict__ tex,   // [6][256][256][32] bf16 HWC
    const void* __restrict__ rayo, const void* __restrict__ rayd,
    const void* __restrict__ w1b, const void* __restrict__ b1b,
    const void* __restrict__ w2b, const void* __restrict__ b2b,
    void* __restrict__ outp, char* __restrict__ pool)
{
    const int t = threadIdx.x;
    unsigned short* fxB = (unsigned short*)(pool + FXB_OFF);   // stride 40 ushort/row
    float* sigL = (float*)(pool + SIG_OFF);
    unsigned short* w1t = (unsigned short*)(pool + WST_OFF);   // [n<64][k<32]
    unsigned short* w2t = (unsigned short*)(pool + W2T_OFF);   // [n<48][k<64]
    float* aL = (float*)(pool + ALP_OFF);                      // alpha -> weights

    // ---- stage weights: LINEAR LDS writes; transpose in the global read index ----
    for (int i = t; i < 2048; i += 512) {        // w1t[i], layout [n][k] stride 32
        const int n = i >> 5, k = i & 31;
        w1t[i] = f2bf_cvt(ldv<F32>(w1b, (size_t)k * 64 + n));
    }
    for (int i = t; i < 3072; i += 512) {        // w2t[i], layout [n][k] stride 64
        const int n = i >> 6, k = i & 63;
        w2t[i] = (n < 33) ? f2bf_cvt(ldv<F32>(w2b, (size_t)k * 33 + n)) : (unsigned short)0;
    }
    __syncthreads();

    // ---- B fragments to registers NOW (records will overwrite w1t/w2t) ----
    // Only MLP waves (w < 4) need them.
    const int w = t >> 6;
    const int lane = t & 63;
    const int l16 = lane & 15, quad = lane >> 4;

    short8 b1f[4];
    short8 b2f[3][2];
    float bb1[4], bb2[3];
    if (w < 4) {
        #pragma unroll
        for (int nt = 0; nt < 4; nt++)
            b1f[nt] = *(const short8*)(pool + WST_OFF + (nt * 16 + l16) * 64 + quad * 16);
        #pragma unroll
        for (int nt = 0; nt < 3; nt++)
            #pragma unroll
            for (int ks = 0; ks < 2; ks++)
                b2f[nt][ks] = *(const short8*)(pool + W2T_OFF + (nt * 16 + l16) * 128 + ks * 64 + quad * 16);
        #pragma unroll
        for (int nt = 0; nt < 4; nt++) bb1[nt] = ldv<F32>(b1b, nt * 16 + l16);
        #pragma unroll
        for (int nt = 0; nt < 3; nt++) {
            const int n2 = nt * 16 + l16;
            bb2[nt] = (n2 < 33) ? ldv<F32>(b2b, n2) : 0.f;
        }
    }
    __syncthreads();   // all w1t/w2t reads done before records overwrite

    // ---- record precompute: thread t<256 = sample row t; weights/indices ONCE ----
    // writer row t: ray rl_w = t>>5, sample s_w = t&31.
    // ji = (s_w>>1) | ((s_w&1)<<4) | (rl_w<<5): reader's 16 concurrent records
    // (fixed k) are ji-consecutive -> 48 B stride -> 2-way banks max + broadcast.
    if (t < 256) {
        const int s = t & 31;
        const int gray = blockIdx.x * RPB + (t >> 5);
        const size_t rb = (size_t)gray * 3;
        const float ox = ldv<F32>(rayo, rb), oy = ldv<F32>(rayo, rb + 1), oz = ldv<F32>(rayo, rb + 2);
        const float dx = ldv<F32>(rayd, rb), dy = ldv<F32>(rayd, rb + 1), dz = ldv<F32>(rayd, rb + 2);
        const float d = 2.25f + 1.05f * ((s + 0.5f) * (1.0f / 32.0f));
        const float x = (ox + d * dx) * 2.0f;
        const float y = (oy + d * dy) * 2.0f;
        const float z = (oz + d * dz) * 2.0f;
        const int ji = ((s >> 1) & 15) | ((s & 1) << 4) | (t & 224);
        char* recp = pool + RECB_OFF + ji * 48;
        #pragma unroll
        for (int p = 0; p < 3; p++) {
            // p0:(x,y)  p1:(y,z)  p2:(x,z)
            const float u = (p == 0) ? x : ((p == 1) ? y : x);
            const float v = (p == 0) ? y : z;
            const float ixf = fmaf(u, 127.5f, 127.5f);
            const float iyf = fmaf(v, 127.5f, 127.5f);
            const float ix0f = floorf(ixf), iy0f = floorf(iyf);
            const float wx1 = ixf - ix0f, wy1 = iyf - iy0f;   // identical to round-0 math
            const int ix0 = iclamp((int)ix0f, 0, 255);
            const int ix1 = iclamp((int)ix0f + 1, 0, 255);
            const int iy0 = iclamp((int)iy0f, 0, 255);
            const int iy1 = iclamp((int)iy0f + 1, 0, 255);
            uint4 rec;
            rec.x = __float_as_uint(wx1);
            rec.y = __float_as_uint(wy1);
            rec.z = (unsigned int)(iy0 * WW + ix0) | ((unsigned int)(iy0 * WW + ix1) << 16);
            rec.w = (unsigned int)(iy1 * WW + ix0) | ((unsigned int)(iy1 * WW + ix1) << 16);
            *(uint4*)(recp + p * 16) = rec;
        }
    }
    __syncthreads();

    // ---- gather: ONE WAVE PER RAY; lane = (channel oct c4, sample subset sub);
    //      2 samples/lane; one dwordx4 per corner (4 lanes cover 64-B texel line) ----
    {
        const int rl = t >> 6;                 // ray in block = wave id
        const int L  = t & 63;
        const int c4 = L & 3;                  // channel oct: ch 8*c4..8*c4+7
        const int sub = L >> 2;                // sample subset 0..15 (2 samples)
        const int gray = blockIdx.x * RPB + rl;
        const int n = gray >> 14;
        const char* texb = (const char*)tex;
        const unsigned int cb = (unsigned int)c4 * 16;  // byte offset of channel oct
        unsigned int pbase[3];
        #pragma unroll
        for (int p = 0; p < 3; p++)
            pbase[p] = (unsigned int)(n * 3 + p) * (HH * WW * CC * 2) + cb;
        const char* recb = pool + RECB_OFF + (sub + (rl << 5)) * 48;

        #pragma unroll 1
        for (int k = 0; k < 2; ++k) {
            const int s = sub * 2 + k;
            const char* recp = recb + (k << 4) * 48;   // ji = sub | (k<<4) | (rl<<5)
            f32x2 a[3][4];                         // [plane][word] = 2 channels
            #pragma unroll
            for (int p = 0; p < 3; p++) {
                const uint4 rc = *(const uint4*)(recp + p * 16);
                const float wx1 = __uint_as_float(rc.x);
                const float wy1 = __uint_as_float(rc.y);
                const float wx0 = 1.f - wx1,  wy0 = 1.f - wy1;
                const float w00 = wx0 * wy0, w01 = wx1 * wy0, w10 = wx0 * wy1, w11 = wx1 * wy1;
                const f32x2 w00p = {w00, w00}, w01p = {w01, w01};
                const f32x2 w10p = {w10, w10}, w11p = {w11, w11};
                const unsigned int pb = pbase[p];
                const uint4 q00 = *(const uint4*)(texb + (pb + ((rc.z & 0xffffu) << 6)));
                const uint4 q01 = *(const uint4*)(texb + (pb + ((rc.z >> 16) << 6)));
                const uint4 q10 = *(const uint4*)(texb + (pb + ((rc.w & 0xffffu) << 6)));
                const uint4 q11 = *(const uint4*)(texb + (pb + ((rc.w >> 16) << 6)));
                const unsigned int* u00 = (const unsigned int*)&q00;
                const unsigned int* u01 = (const unsigned int*)&q01;
                const unsigned int* u10 = (const unsigned int*)&q10;
                const unsigned int* u11 = (const unsigned int*)&q11;
                #pragma unroll
                for (int i = 0; i < 4; i++) {      // word i = channels (2i, 2i+1)
                    f32x2 acc = pk_mul(w00p, unpk2(u00[i]));   // same order as scalar:
                    acc = pk_fma(w01p, unpk2(u01[i]), acc);    // w00*v00 +w01 +w10 +w11
                    acc = pk_fma(w10p, unpk2(u10[i]), acc);
                    acc = pk_fma(w11p, unpk2(u11[i]), acc);
                    a[p][i] = acc;
                }
            }
            // plane average ((a0+a1)+a2)*(1/3) packed, then 8 ch -> one b128 write
            const f32x2 third = {1.0f / 3.0f, 1.0f / 3.0f};
            uint4 pk;
            f32x2 s0 = pk_mul(pk_add(pk_add(a[0][0], a[1][0]), a[2][0]), third);
            f32x2 s1 = pk_mul(pk_add(pk_add(a[0][1], a[1][1]), a[2][1]), third);
            f32x2 s2 = pk_mul(pk_add(pk_add(a[0][2], a[1][2]), a[2][2]), third);
            f32x2 s3 = pk_mul(pk_add(pk_add(a[0][3], a[1][3]), a[2][3]), third);
            pk.x = cvtpk2(s0.x, s0.y);
            pk.y = cvtpk2(s1.x, s1.y);
            pk.z = cvtpk2(s2.x, s2.y);
            pk.w = cvtpk2(s3.x, s3.y);
            *(uint4*)(pool + FXB_OFF + (rl * 32 + s) * 80 + c4 * 16) = pk;
        }
    }
    __syncthreads();   // fxB ready; records dead (SIG/hb/ALP writers start below)

    // ---- MFMA MLP: waves 0..3, wave w owns sample rows [64w, 64w+64) ----
    if (w < 4) {
        char* hb = pool + WST_OFF + w * 2304;    // 16 rows x 144 B
        #pragma unroll 1
        for (int mt = 0; mt < 4; mt++) {
            const int rbase = w * 64 + mt * 16;
            const short8 a1 = *(const short8*)(pool + FXB_OFF + (rbase + l16) * 80 + quad * 16);
            #pragma unroll
            for (int nt = 0; nt < 4; nt++) {
                f32x4 hc = { bb1[nt], bb1[nt], bb1[nt], bb1[nt] };
                hc = mfma16(a1, b1f[nt], hc);
                #pragma unroll
                for (int r = 0; r < 4; r++) {
                    const float hv = softplus_fast(hc[r]);
                    *(unsigned short*)(hb + (quad * 4 + r) * 144 + (nt * 16 + l16) * 2) = f2bf_cvt(hv);
                }
            }
            const short8 a2k0 = *(const short8*)(hb + l16 * 144 + quad * 16);
            const short8 a2k1 = *(const short8*)(hb + l16 * 144 + 64 + quad * 16);
            #pragma unroll
            for (int nt = 0; nt < 3; nt++) {
                f32x4 o = { bb2[nt], bb2[nt], bb2[nt], bb2[nt] };
                o = mfma16(a2k0, b2f[nt][0], o);
                o = mfma16(a2k1, b2f[nt][1], o);
                #pragma unroll
                for (int r = 0; r < 4; r++) {
                    const int row = rbase + quad * 4 + r;
                    if (nt == 0) {
                        if (l16 == 0) sigL[row] = o[r];                      // raw sigma (n=0)
                        else fxB[row * 40 + (l16 - 1)] =
                                 f2bf_cvt(fmaf(sigmoid_fast(o[r]), 1.002f, -0.001f));   // ch 0..14
                    } else if (nt == 1) {
                        fxB[row * 40 + (15 + l16)] =
                                 f2bf_cvt(fmaf(sigmoid_fast(o[r]), 1.002f, -0.001f));   // ch 15..30
                    } else if (l16 == 0) {
                        fxB[row * 40 + 31] =
                                 f2bf_cvt(fmaf(sigmoid_fast(o[r]), 1.002f, -0.001f));   // ch 31
                    }
                }
            }
        }
    }
    __syncthreads();

    // ---- marcher phase 1: thread t<256 = (ray rl, interval sm) computes alpha ----
    if (t < 256) {
        const int rl = t >> 5, sm = t & 31;
        if (sm < 31) {
            const float sp = sigL[rl * 32 + sm];
            const float sn = sigL[rl * 32 + sm + 1];
            const float m = 0.5f * (sp + sn) - 1.0f;
            const float dens = fmaxf(m, 0.f) + __logf(1.0f + __expf(-fabsf(m)));
            aL[rl * 32 + sm] = 1.0f - __expf(-(1.05f / 32.0f) * dens);
        }
    }
    __syncthreads();

    // ---- marcher phase 2: one lane per ray does the serial T-scan -> 0.5*alpha*T ----
    if (t < 256) {
        const int rl = t >> 5, sm = t & 31;
        if (sm == 0) {
            float T = 1.0f;
            #pragma unroll
            for (int j = 0; j < 31; j++) {
                const float a = aL[rl * 32 + j];
                aL[rl * 32 + j] = (a * T) * 0.5f;
                T *= (1.0f - a + 1e-10f);
            }
        }
    }
    __syncthreads();

    // ---- marcher phase 3: pure FMA channel walk ----
    if (t < 256) {
        const int rl = t >> 5, c = t & 31;
        const int gr2 = blockIdx.x * RPB + rl;
        float acc = 0.0f;
        float rp = bf2f(fxB[(rl * 32 + 0) * 40 + c]);
        #pragma unroll 4
        for (int sm = 0; sm < 31; sm++) {
            const float rn = bf2f(fxB[(rl * 32 + sm + 1) * 40 + c]);
            acc = fmaf(aL[rl * 32 + sm], rp + rn, acc);
            rp = rn;
        }
        const size_t oidx = (size_t)gr2 * 32 + c;
        if (F32) ((float*)outp)[oidx] = acc;
        else     ((unsigned short*)outp)[oidx] = f2bf_cvt(acc);
    }
}

__global__ __launch_bounds__(512, 4) void render_fast(
    const unsigned short* __restrict__ tex, const void* __restrict__ rayo,
    const void* __restrict__ rayd, const void* __restrict__ w1b,
    const void* __restrict__ b1b, const void* __restrict__ w2b,
    const void* __restrict__ b2b, void* __restrict__ outp)
{
    __shared__ __align__(16) char pool[POOLSZ];
    const int t = threadIdx.x;
    if (t == 0) *(int*)pool = detect_f32_local(rayo);   // FXB space: dead until gather
    __syncthreads();
    const int f32flag = *(const int*)pool;   // every thread reads BEFORE staging barrier
    if (f32flag) render_mfma_body<true >(tex, rayo, rayd, w1b, b1b, w2b, b2b, outp, pool);
    else         render_mfma_body<false>(tex, rayo, rayd, w1b, b1b, w2b, b2b, outp, pool);
}

// ================= no-workspace fallback (round-3 verified) =================
template<bool F32>
__device__ __forceinline__ void render_body(
    const void* __restrict__ vol, const void* __restrict__ rayo,
    const void* __restrict__ rayd, const void* __restrict__ w1b,
    const void* __restrict__ b1b, const void* __restrict__ w2b,
    const void* __restrict__ b2b, void* __restrict__ outp,
    float* wsm, float (*rgbL)[SS][33], float (*sigL)[SS])
{
    const int t = threadIdx.x;
    for (int i = t; i < 4257; i += 256) {
        float v;
        if (i < 2048)       v = ldv<F32>(w1b, i);
        else if (i < 2112)  v = ldv<F32>(b1b, i - 2048);
        else if (i < 4224)  v = ldv<F32>(w2b, i - 2112);
        else                v = ldv<F32>(b2b, i - 4224);
        wsm[i] = v;
    }
    __syncthreads();

    const int rl = t >> 5;
    const int s  = t & 31;
    const int gray = blockIdx.x * RPB + rl;
    const int n = gray >> 14;

    const size_t rbase = (size_t)gray * 3;
    const float ox = ldv<F32>(rayo, rbase), oy = ldv<F32>(rayo, rbase + 1), oz = ldv<F32>(rayo, rbase + 2);
    const float dx = ldv<F32>(rayd, rbase), dy = ldv<F32>(rayd, rbase + 1), dz = ldv<F32>(rayd, rbase + 2);
    const float d = 2.25f + 1.05f * ((s + 0.5f) * (1.0f / 32.0f));
    const float x = (ox + d * dx) * 2.0f;
    const float y = (oy + d * dy) * 2.0f;
    const float z = (oz + d * dz) * 2.0f;

    float fx[32];
    #pragma unroll
    for (int c = 0; c < 32; c++) fx[c] = 0.f;

    #pragma unroll
    for (int p = 0; p < 3; p++) {
        const float u = (p == 0) ? x : ((p == 1) ? y : x);
        const float v = (p == 0) ? y : z;
        const float ixf = fmaf(u, 127.5f, 127.5f);
        const float iyf = fmaf(v, 127.5f, 127.5f);
        const float ix0f = floorf(ixf), iy0f = floorf(iyf);
        const float wx1 = ixf - ix0f, wy1 = iyf - iy0f;
        const float wx0 = 1.f - wx1,  wy0 = 1.f - wy1;
        const int ix0 = iclamp((int)ix0f, 0, 255);
        const int ix1 = iclamp((int)ix0f + 1, 0, 255);
        const int iy0 = iclamp((int)iy0f, 0, 255);
        const int iy1 = iclamp((int)iy0f + 1, 0, 255);
        const float wnw = wx0 * wy0, wne = wx1 * wy0, wsw = wx0 * wy1, wse = wx1 * wy1;
        const int i00 = iy0 * WW + ix0, i01 = iy0 * WW + ix1;
        const int i10 = iy1 * WW + ix0, i11 = iy1 * WW + ix1;
        const size_t pb = (size_t)(n * 3 + p) * CC * HH * WW;
        #pragma unroll
        for (int c = 0; c < 32; c++) {
            const size_t cb = pb + (size_t)c * (HH * WW);
            fx[c] += wnw * ldv<F32>(vol, cb + i00) + wne * ldv<F32>(vol, cb + i01)
                   + wsw * ldv<F32>(vol, cb + i10) + wse * ldv<F32>(vol, cb + i11);
        }
    }
    #pragma unroll
    for (int c = 0; c < 32; c++) fx[c] *= (1.0f / 3.0f);

    const float* W1 = wsm;
    const float* B1 = wsm + 2048;
    const float* W2 = wsm + 2112;
    const float* B2 = wsm + 4224;

    float h[64];
    #pragma unroll
    for (int j = 0; j < 64; j++) h[j] = B1[j];
    #pragma unroll
    for (int c = 0; c < 32; c++) {
        const float f = fx[c];
        #pragma unroll
        for (int j = 0; j < 64; j++) h[j] = fmaf(f, W1[c * 64 + j], h[j]);
    }
    #pragma unroll
    for (int j = 0; j < 64; j++) h[j] = softplus_f(h[j]);

    #pragma unroll 1
    for (int k = 0; k < 33; k++) {
        float zz = B2[k];
        #pragma unroll
        for (int j = 0; j < 64; j++) zz = fmaf(h[j], W2[j * 33 + k], zz);
        if (k == 0) sigL[rl][s] = zz;
        else {
            const float sg = 1.0f / (1.0f + expf(-zz));
            rgbL[rl][s][k - 1] = fmaf(sg, 1.002f, -0.001f);
        }
    }
    __syncthreads();

    const int c = t & 31;
    const float delta = 1.05f / 32.0f;
    float T = 1.0f, acc = 0.0f;
    float sig_prev = sigL[rl][0];
    float rgb_prev = rgbL[rl][0][c];
    #pragma unroll 1
    for (int sm = 0; sm < 31; sm++) {
        const float sig_next = sigL[rl][sm + 1];
        const float rgb_next = rgbL[rl][sm + 1][c];
        const float dens = softplus_f(0.5f * (sig_prev + sig_next) - 1.0f);
        const float alpha = 1.0f - expf(-delta * dens);
        acc += alpha * T * 0.5f * (rgb_prev + rgb_next);
        T *= (1.0f - alpha + 1e-10f);
        sig_prev = sig_next;
        rgb_prev = rgb_next;
    }
    const size_t oidx = (size_t)gray * 32 + c;
    if (F32) ((float*)outp)[oidx] = acc;
    else     ((unsigned short*)outp)[oidx] = f2bf_cvt(acc);
}

__global__ __launch_bounds__(256) void render_any(
    const void* __restrict__ vol, const void* __restrict__ rayo,
    const void* __restrict__ rayd, const void* __restrict__ w1b,
    const void* __restrict__ b1b, const void* __restrict__ w2b,
    const void* __restrict__ b2b, void* __restrict__ outp)
{
    __shared__ float wsm[4257];
    __shared__ float rgbL[RPB][SS][33];
    __shared__ float sigL[RPB][SS];
    __shared__ int sflag;
    if (threadIdx.x == 0) sflag = detect_f32_local(rayo);
    __syncthreads();
    const int f32flag = sflag;
    __syncthreads();
    if (f32flag) render_body<true >(vol, rayo, rayd, w1b, b1b, w2b, b2b, outp, wsm, rgbL, sigL);
    else         render_body<false>(vol, rayo, rayd, w1b, b1b, w2b, b2b, outp, wsm, rgbL, sigL);
}

extern "C" void kernel_launch(void* const* d_in, const int* in_sizes, int n_in,
                              void* d_out, int out_size, void* d_ws, size_t ws_size,
                              hipStream_t stream) {
    const void* vol  = d_in[0];
    const void* rayo = d_in[1];
    const void* rayd = d_in[2];
    const void* w1   = d_in[3];
    const void* b1   = d_in[4];
    const void* w2   = d_in[5];
    const void* b2   = d_in[6];
    unsigned short* tex = (unsigned short*)((char*)d_ws + TEXOFF);

    const size_t need = TEXOFF + TEXBYTES;   // bf16 texture always

    if (ws_size >= need) {
        transpose_tex<<<dim3(8 * HH, 6), dim3(256), 0, stream>>>(vol, tex, rayo);
        render_fast<<<dim3(NRAYS / RPB), dim3(512), 0, stream>>>(
            tex, rayo, rayd, w1, b1, w2, b2, d_out);
    } else {
        render_any<<<dim3(NRAYS / RPB), dim3(256), 0, stream>>>(
            vol, rayo, rayd, w1, b1, w2, b2, d_out);
    }
}

// Round 12
// 220.288 us; speedup vs baseline: 1.7108x; 1.0663x over previous
//
#include <hip/hip_runtime.h>
#include <math.h>

// Problem constants (from reference)
#define HH 256
#define WW 256
#define CC 32
#define SS 32
#define NRAYS 32768            // N*R = 2*16384
#define RPB 8                  // rays per block
#define TEXOFF 256             // byte offset of HWC bf16 texture in d_ws
#define TEXBYTES ((size_t)6 * HH * WW * CC * 2)

// LDS pool layout (bytes, all 16-aligned)
#define FXB_OFF 0              // 256 rows x 80 B (32 bf16 ch in bytes [0,64))
#define SIG_OFF 20480          // f32[256] raw sigma (post-gather)
#define WST_OFF 21504          // w1t 4096 B | w2t 6144 B; dies after fragment preload
#define W2T_OFF 25600
#define ALP_OFF 31744          // f32[256] alpha->weights (post-gather)
#define POOLSZ  32768          // exactly 32 KB -> 5 blocks/CU by LDS
#define RECB_OFF 20480         // during gather: 256 x 48 B bilinear records
// NOTE: no __syncthreads_or (hidden 512 B LDS scratch, r4: occupancy -25%).
// NOTE r10/r11: 512-thread shapes are NOT faster (r11: 146 vs 130 us) — waves 4-7
// idle in MLP, 8-wave barriers. Keep 256 threads, 5 blocks/CU.
// NOTE r10: launch_bounds min-waves too high forces VGPR spill (WRITE 4->386 MB).

typedef __attribute__((ext_vector_type(8))) short short8;   // 8 bf16
typedef __attribute__((ext_vector_type(4))) float f32x4;
typedef __attribute__((ext_vector_type(2))) float f32x2;

__device__ __forceinline__ f32x4 mfma16(short8 a, short8 b, f32x4 c) {
    return __builtin_amdgcn_mfma_f32_16x16x32_bf16(a, b, c, 0, 0, 0);
}

// ---------- helpers ----------
__device__ __forceinline__ float bf2f(unsigned short u) {
    union { unsigned int ui; float f; } v; v.ui = ((unsigned int)u) << 16; return v.f;
}
__device__ __forceinline__ float lo2f(unsigned int w) {
    union { unsigned int ui; float f; } v; v.ui = w << 16; return v.f;
}
__device__ __forceinline__ float hi2f(unsigned int w) {
    union { unsigned int ui; float f; } v; v.ui = w & 0xffff0000u; return v.f;
}
// HW packed f32->bf16 (RNE, 1 instr for 2 values)
__device__ __forceinline__ unsigned int cvtpk2(float a, float b) {
    unsigned int r;
    asm("v_cvt_pk_bf16_f32 %0, %1, %2" : "=v"(r) : "v"(a), "v"(b));
    return r;
}
__device__ __forceinline__ unsigned short f2bf_cvt(float f) {
    unsigned int r;
    asm("v_cvt_pk_bf16_f32 %0, %1, %2" : "=v"(r) : "v"(f), "v"(f));
    return (unsigned short)r;
}
// packed 2xf32 math (CDNA4 v_pk_*_f32; IEEE per half — bit-identical to scalar)
__device__ __forceinline__ f32x2 pk_mul(f32x2 a, f32x2 b) {
    f32x2 d; asm("v_pk_mul_f32 %0, %1, %2" : "=v"(d) : "v"(a), "v"(b)); return d;
}
__device__ __forceinline__ f32x2 pk_fma(f32x2 a, f32x2 b, f32x2 c) {
    f32x2 d; asm("v_pk_fma_f32 %0, %1, %2, %3" : "=v"(d) : "v"(a), "v"(b), "v"(c)); return d;
}
__device__ __forceinline__ f32x2 pk_add(f32x2 a, f32x2 b) {
    f32x2 d; asm("v_pk_add_f32 %0, %1, %2" : "=v"(d) : "v"(a), "v"(b)); return d;
}
__device__ __forceinline__ f32x2 unpk2(unsigned int w) {   // (lo bf16, hi bf16) -> 2xf32
    f32x2 d; d.x = lo2f(w); d.y = hi2f(w); return d;
}
__device__ __forceinline__ int iclamp(int x, int lo, int hi) {
    return x < lo ? lo : (x > hi ? hi : x);
}
__device__ __forceinline__ float softplus_f(float z) {       // precise (fallback)
    return fmaxf(z, 0.f) + log1pf(expf(-fabsf(z)));
}
__device__ __forceinline__ float softplus_fast(float z) {
    return fmaxf(z, 0.f) + __logf(1.0f + __expf(-fabsf(z)));
}
__device__ __forceinline__ float sigmoid_fast(float z) {
    return __builtin_amdgcn_rcpf(1.0f + __expf(-z));
}

template<bool F32>
__device__ __forceinline__ float ldv(const void* p, size_t i) {
    if (F32) return ((const float*)p)[i];
    else     return bf2f(((const unsigned short*)p)[i]);
}

// ---------- dtype detection (in-kernel): |ray_origin| == 2.7 by construction ----------
__device__ __forceinline__ int detect_f32_local(const void* __restrict__ rayo) {
    const float* f = (const float*)rayo;
    const unsigned short* u = (const unsigned short*)rayo;
    float sf = 0.f, sb = 0.f;
    #pragma unroll
    for (int i = 0; i < 8; ++i) {
        const float a = f[3 * i], b = f[3 * i + 1], c = f[3 * i + 2];
        const float nf = a * a + b * b + c * c;
        sf += fminf(fabsf(nf - 7.29f), 1e3f);            // fminf(NaN,x)=x -> NaN-safe
        const float x = bf2f(u[3 * i]), y = bf2f(u[3 * i + 1]), z = bf2f(u[3 * i + 2]);
        const float nb = x * x + y * y + z * z;
        sb += fminf(fabsf(nb - 7.29f), 1e3f);
    }
    return (sf < sb) ? 1 : 0;
}

// ---------- CHW -> HWC transpose; OUTPUT ALWAYS bf16 (r8 shape, verified r9) ----------
__global__ __launch_bounds__(256) void transpose_tex(
    const void* __restrict__ vol, unsigned short* __restrict__ tex,
    const void* __restrict__ rayo) {
    __shared__ __align__(16) unsigned short tb[32][36];   // 72 B rows: ~2-way banks
    __shared__ int sflag;
    const int l = threadIdx.x;
    if (l == 0) sflag = detect_f32_local(rayo);
    const int tx = l & 7, ty = l >> 3;     // phase 1: c = ty (0..31), w-quad = tx (0..7)
    const int wq = l >> 3, cq = l & 7;     // phase 2: w = w0+wq (0..31), c-quad = cq
    const int w0 = (blockIdx.x & 7) * 32;
    const int h  = blockIdx.x >> 3;
    const int img = blockIdx.y;
    const size_t srcE = (((size_t)img * CC + ty) * HH + h) * WW + w0 + 4 * tx;
    const size_t dstE = (((size_t)img * HH + h) * WW + (w0 + wq)) * CC + 4 * cq;
    __syncthreads();
    if (sflag) {
        const float4 v = *(const float4*)((const float*)vol + srcE);
        tb[ty][4 * tx + 0] = f2bf_cvt(v.x); tb[ty][4 * tx + 1] = f2bf_cvt(v.y);
        tb[ty][4 * tx + 2] = f2bf_cvt(v.z); tb[ty][4 * tx + 3] = f2bf_cvt(v.w);
    } else {
        *(ushort4*)&tb[ty][4 * tx] = *(const ushort4*)((const unsigned short*)vol + srcE);
    }
    __syncthreads();
    ushort4 o;
    o.x = tb[4 * cq + 0][wq]; o.y = tb[4 * cq + 1][wq];
    o.z = tb[4 * cq + 2][wq]; o.w = tb[4 * cq + 3][wq];
    *(ushort4*)(tex + dstE) = o;
}

// ================= fast path: bf16 gather + MFMA MLP + split marcher =================
template<bool F32>
__device__ void render_mfma_body(
    const unsigned short* __restrict__ tex,   // [6][256][256][32] bf16 HWC
    const void* __restrict__ rayo, const void* __restrict__ rayd,
    const void* __restrict__ w1b, const void* __restrict__ b1b,
    const void* __restrict__ w2b, const void* __restrict__ b2b,
    void* __restrict__ outp, char* __restrict__ pool)
{
    const int t = threadIdx.x;
    unsigned short* fxB = (unsigned short*)(pool + FXB_OFF);   // stride 40 ushort/row
    float* sigL = (float*)(pool + SIG_OFF);
    unsigned short* w1t = (unsigned short*)(pool + WST_OFF);   // [n<64][k<32]
    unsigned short* w2t = (unsigned short*)(pool + W2T_OFF);   // [n<48][k<64]
    float* aL = (float*)(pool + ALP_OFF);                      // alpha -> weights

    // ---- stage weights: LINEAR LDS writes; transpose in the global read index ----
    for (int i = t; i < 2048; i += 256) {        // w1t[i], layout [n][k] stride 32
        const int n = i >> 5, k = i & 31;
        w1t[i] = f2bf_cvt(ldv<F32>(w1b, (size_t)k * 64 + n));
    }
    for (int i = t; i < 3072; i += 256) {        // w2t[i], layout [n][k] stride 64
        const int n = i >> 6, k = i & 63;
        w2t[i] = (n < 33) ? f2bf_cvt(ldv<F32>(w2b, (size_t)k * 33 + n)) : (unsigned short)0;
    }
    __syncthreads();

    // ---- B fragments to registers NOW (records will overwrite w1t/w2t) ----
    const int w = t >> 6;
    const int lane = t & 63;
    const int l16 = lane & 15, quad = lane >> 4;

    short8 b1f[4];
    #pragma unroll
    for (int nt = 0; nt < 4; nt++)
        b1f[nt] = *(const short8*)(pool + WST_OFF + (nt * 16 + l16) * 64 + quad * 16);
    short8 b2f[3][2];
    #pragma unroll
    for (int nt = 0; nt < 3; nt++)
        #pragma unroll
        for (int ks = 0; ks < 2; ks++)
            b2f[nt][ks] = *(const short8*)(pool + W2T_OFF + (nt * 16 + l16) * 128 + ks * 64 + quad * 16);
    __syncthreads();   // all w1t/w2t reads done before records overwrite

    // ---- record precompute: thread t = sample row t; weights/indices ONCE ----
    // row (rl, s=sub*4+k) stored at ji = sub | (k<<3) | (rl<<5): the 16 records a
    // wave reads concurrently (fixed k) then span 8 distinct 16B bank-slots
    // (2-way max = free); 4 lanes sharing a record broadcast.
    {
        const int s = t & 31;
        const int gray = blockIdx.x * RPB + (t >> 5);
        const size_t rb = (size_t)gray * 3;
        const float ox = ldv<F32>(rayo, rb), oy = ldv<F32>(rayo, rb + 1), oz = ldv<F32>(rayo, rb + 2);
        const float dx = ldv<F32>(rayd, rb), dy = ldv<F32>(rayd, rb + 1), dz = ldv<F32>(rayd, rb + 2);
        const float d = 2.25f + 1.05f * ((s + 0.5f) * (1.0f / 32.0f));
        const float x = (ox + d * dx) * 2.0f;
        const float y = (oy + d * dy) * 2.0f;
        const float z = (oz + d * dz) * 2.0f;
        const int ji = ((s >> 2) & 7) | ((s & 3) << 3) | (t & 224);
        char* recp = pool + RECB_OFF + ji * 48;
        #pragma unroll
        for (int p = 0; p < 3; p++) {
            // p0:(x,y)  p1:(y,z)  p2:(x,z)
            const float u = (p == 0) ? x : ((p == 1) ? y : x);
            const float v = (p == 0) ? y : z;
            const float ixf = fmaf(u, 127.5f, 127.5f);
            const float iyf = fmaf(v, 127.5f, 127.5f);
            const float ix0f = floorf(ixf), iy0f = floorf(iyf);
            const float wx1 = ixf - ix0f, wy1 = iyf - iy0f;   // identical to round-0 math
            const int ix0 = iclamp((int)ix0f, 0, 255);
            const int ix1 = iclamp((int)ix0f + 1, 0, 255);
            const int iy0 = iclamp((int)iy0f, 0, 255);
            const int iy1 = iclamp((int)iy0f + 1, 0, 255);
            uint4 rec;
            rec.x = __float_as_uint(wx1);
            rec.y = __float_as_uint(wy1);
            rec.z = (unsigned int)(iy0 * WW + ix0) | ((unsigned int)(iy0 * WW + ix1) << 16);
            rec.w = (unsigned int)(iy1 * WW + ix0) | ((unsigned int)(iy1 * WW + ix1) << 16);
            *(uint4*)(recp + p * 16) = rec;
        }
    }
    __syncthreads();

    // ---- gather: 4-lane sub-group per (ray, sample-subset); lane = 8 channels;
    //      one dwordx4 per corner (4 lanes cover the full 64-B texel line).
    //      r12: unroll 2 -> two independent sample chains in flight (ILP probe) ----
    {
        const int rl = t >> 5;                 // ray in block
        const int L  = t & 31;
        const int c4 = L & 3;                  // channel oct: ch 8*c4..8*c4+7
        const int sub = L >> 2;                // sample subset 0..7 (4 samples)
        const int gray = blockIdx.x * RPB + rl;
        const int n = gray >> 14;
        const char* texb = (const char*)tex;
        const unsigned int cb = (unsigned int)c4 * 16;  // byte offset of channel oct
        unsigned int pbase[3];
        #pragma unroll
        for (int p = 0; p < 3; p++)
            pbase[p] = (unsigned int)(n * 3 + p) * (HH * WW * CC * 2) + cb;
        const char* recb = pool + RECB_OFF + (sub + (rl << 5)) * 48;

        #pragma unroll 2
        for (int k = 0; k < 4; ++k) {
            const int s = sub * 4 + k;
            const char* recp = recb + k * 384;     // ji = sub + 8k + 32rl
            f32x2 a[3][4];                         // [plane][word] = 2 channels
            #pragma unroll
            for (int p = 0; p < 3; p++) {
                const uint4 rc = *(const uint4*)(recp + p * 16);
                const float wx1 = __uint_as_float(rc.x);
                const float wy1 = __uint_as_float(rc.y);
                const float wx0 = 1.f - wx1,  wy0 = 1.f - wy1;
                const float w00 = wx0 * wy0, w01 = wx1 * wy0, w10 = wx0 * wy1, w11 = wx1 * wy1;
                const f32x2 w00p = {w00, w00}, w01p = {w01, w01};
                const f32x2 w10p = {w10, w10}, w11p = {w11, w11};
                const unsigned int pb = pbase[p];
                const uint4 q00 = *(const uint4*)(texb + (pb + ((rc.z & 0xffffu) << 6)));
                const uint4 q01 = *(const uint4*)(texb + (pb + ((rc.z >> 16) << 6)));
                const uint4 q10 = *(const uint4*)(texb + (pb + ((rc.w & 0xffffu) << 6)));
                const uint4 q11 = *(const uint4*)(texb + (pb + ((rc.w >> 16) << 6)));
                const unsigned int* u00 = (const unsigned int*)&q00;
                const unsigned int* u01 = (const unsigned int*)&q01;
                const unsigned int* u10 = (const unsigned int*)&q10;
                const unsigned int* u11 = (const unsigned int*)&q11;
                #pragma unroll
                for (int i = 0; i < 4; i++) {      // word i = channels (2i, 2i+1)
                    f32x2 acc = pk_mul(w00p, unpk2(u00[i]));   // same order as scalar:
                    acc = pk_fma(w01p, unpk2(u01[i]), acc);    // w00*v00 +w01 +w10 +w11
                    acc = pk_fma(w10p, unpk2(u10[i]), acc);
                    acc = pk_fma(w11p, unpk2(u11[i]), acc);
                    a[p][i] = acc;
                }
            }
            // plane average ((a0+a1)+a2)*(1/3) packed, then 8 ch -> one b128 write
            const f32x2 third = {1.0f / 3.0f, 1.0f / 3.0f};
            uint4 pk;
            f32x2 s0 = pk_mul(pk_add(pk_add(a[0][0], a[1][0]), a[2][0]), third);
            f32x2 s1 = pk_mul(pk_add(pk_add(a[0][1], a[1][1]), a[2][1]), third);
            f32x2 s2 = pk_mul(pk_add(pk_add(a[0][2], a[1][2]), a[2][2]), third);
            f32x2 s3 = pk_mul(pk_add(pk_add(a[0][3], a[1][3]), a[2][3]), third);
            pk.x = cvtpk2(s0.x, s0.y);
            pk.y = cvtpk2(s1.x, s1.y);
            pk.z = cvtpk2(s2.x, s2.y);
            pk.w = cvtpk2(s3.x, s3.y);
            *(uint4*)(pool + FXB_OFF + (rl * 32 + s) * 80 + c4 * 16) = pk;
        }
    }

    // ---- bias loads (tiny, L2-hot; issued before barrier to hide latency) ----
    float bb1[4], bb2[3];
    #pragma unroll
    for (int nt = 0; nt < 4; nt++) bb1[nt] = ldv<F32>(b1b, nt * 16 + l16);
    #pragma unroll
    for (int nt = 0; nt < 3; nt++) {
        const int n2 = nt * 16 + l16;
        bb2[nt] = (n2 < 33) ? ldv<F32>(b2b, n2) : 0.f;
    }
    __syncthreads();   // fxB ready; records dead (SIG/hb/ALP writers start below)

    // ---- MFMA MLP: wave w owns sample rows [64w, 64w+64) ----
    {
        char* hb = pool + WST_OFF + w * 2304;    // 16 rows x 144 B
        #pragma unroll 1
        for (int mt = 0; mt < 4; mt++) {
            const int rbase = w * 64 + mt * 16;
            const short8 a1 = *(const short8*)(pool + FXB_OFF + (rbase + l16) * 80 + quad * 16);
            #pragma unroll
            for (int nt = 0; nt < 4; nt++) {
                f32x4 hc = { bb1[nt], bb1[nt], bb1[nt], bb1[nt] };
                hc = mfma16(a1, b1f[nt], hc);
                #pragma unroll
                for (int r = 0; r < 4; r++) {
                    const float hv = softplus_fast(hc[r]);
                    *(unsigned short*)(hb + (quad * 4 + r) * 144 + (nt * 16 + l16) * 2) = f2bf_cvt(hv);
                }
            }
            const short8 a2k0 = *(const short8*)(hb + l16 * 144 + quad * 16);
            const short8 a2k1 = *(const short8*)(hb + l16 * 144 + 64 + quad * 16);
            #pragma unroll
            for (int nt = 0; nt < 3; nt++) {
                f32x4 o = { bb2[nt], bb2[nt], bb2[nt], bb2[nt] };
                o = mfma16(a2k0, b2f[nt][0], o);
                o = mfma16(a2k1, b2f[nt][1], o);
                #pragma unroll
                for (int r = 0; r < 4; r++) {
                    const int row = rbase + quad * 4 + r;
                    if (nt == 0) {
                        if (l16 == 0) sigL[row] = o[r];                      // raw sigma (n=0)
                        else fxB[row * 40 + (l16 - 1)] =
                                 f2bf_cvt(fmaf(sigmoid_fast(o[r]), 1.002f, -0.001f));   // ch 0..14
                    } else if (nt == 1) {
                        fxB[row * 40 + (15 + l16)] =
                                 f2bf_cvt(fmaf(sigmoid_fast(o[r]), 1.002f, -0.001f));   // ch 15..30
                    } else if (l16 == 0) {
                        fxB[row * 40 + 31] =
                                 f2bf_cvt(fmaf(sigmoid_fast(o[r]), 1.002f, -0.001f));   // ch 31
                    }
                }
            }
        }
    }
    __syncthreads();

    // ---- marcher phase 1: thread t = (ray rl, interval sm) computes alpha once ----
    {
        const int rl = t >> 5, sm = t & 31;
        if (sm < 31) {
            const float sp = sigL[rl * 32 + sm];
            const float sn = sigL[rl * 32 + sm + 1];
            const float m = 0.5f * (sp + sn) - 1.0f;
            const float dens = fmaxf(m, 0.f) + __logf(1.0f + __expf(-fabsf(m)));
            aL[rl * 32 + sm] = 1.0f - __expf(-(1.05f / 32.0f) * dens);
        }
    }
    __syncthreads();

    // ---- marcher phase 2: one lane per ray does the serial T-scan -> 0.5*alpha*T ----
    {
        const int rl = t >> 5, sm = t & 31;
        if (sm == 0) {
            float T = 1.0f;
            #pragma unroll
            for (int j = 0; j < 31; j++) {
                const float a = aL[rl * 32 + j];
                aL[rl * 32 + j] = (a * T) * 0.5f;
                T *= (1.0f - a + 1e-10f);
            }
        }
    }
    __syncthreads();

    // ---- marcher phase 3: pure FMA channel walk ----
    {
        const int rl = t >> 5, c = t & 31;
        const int gr2 = blockIdx.x * RPB + rl;
        float acc = 0.0f;
        float rp = bf2f(fxB[(rl * 32 + 0) * 40 + c]);
        #pragma unroll 4
        for (int sm = 0; sm < 31; sm++) {
            const float rn = bf2f(fxB[(rl * 32 + sm + 1) * 40 + c]);
            acc = fmaf(aL[rl * 32 + sm], rp + rn, acc);
            rp = rn;
        }
        const size_t oidx = (size_t)gr2 * 32 + c;
        if (F32) ((float*)outp)[oidx] = acc;
        else     ((unsigned short*)outp)[oidx] = f2bf_cvt(acc);
    }
}

__global__ __launch_bounds__(256, 5) void render_fast(
    const unsigned short* __restrict__ tex, const void* __restrict__ rayo,
    const void* __restrict__ rayd, const void* __restrict__ w1b,
    const void* __restrict__ b1b, const void* __restrict__ w2b,
    const void* __restrict__ b2b, void* __restrict__ outp)
{
    __shared__ __align__(16) char pool[POOLSZ];
    const int t = threadIdx.x;
    if (t == 0) *(int*)pool = detect_f32_local(rayo);   // FXB space: dead until gather
    __syncthreads();
    const int f32flag = *(const int*)pool;   // every thread reads BEFORE staging barrier
    if (f32flag) render_mfma_body<true >(tex, rayo, rayd, w1b, b1b, w2b, b2b, outp, pool);
    else         render_mfma_body<false>(tex, rayo, rayd, w1b, b1b, w2b, b2b, outp, pool);
}

// ================= no-workspace fallback (round-3 verified) =================
template<bool F32>
__device__ __forceinline__ void render_body(
    const void* __restrict__ vol, const void* __restrict__ rayo,
    const void* __restrict__ rayd, const void* __restrict__ w1b,
    const void* __restrict__ b1b, const void* __restrict__ w2b,
    const void* __restrict__ b2b, void* __restrict__ outp,
    float* wsm, float (*rgbL)[SS][33], float (*sigL)[SS])
{
    const int t = threadIdx.x;
    for (int i = t; i < 4257; i += 256) {
        float v;
        if (i < 2048)       v = ldv<F32>(w1b, i);
        else if (i < 2112)  v = ldv<F32>(b1b, i - 2048);
        else if (i < 4224)  v = ldv<F32>(w2b, i - 2112);
        else                v = ldv<F32>(b2b, i - 4224);
        wsm[i] = v;
    }
    __syncthreads();

    const int rl = t >> 5;
    const int s  = t & 31;
    const int gray = blockIdx.x * RPB + rl;
    const int n = gray >> 14;

    const size_t rbase = (size_t)gray * 3;
    const float ox = ldv<F32>(rayo, rbase), oy = ldv<F32>(rayo, rbase + 1), oz = ldv<F32>(rayo, rbase + 2);
    const float dx = ldv<F32>(rayd, rbase), dy = ldv<F32>(rayd, rbase + 1), dz = ldv<F32>(rayd, rbase + 2);
    const float d = 2.25f + 1.05f * ((s + 0.5f) * (1.0f / 32.0f));
    const float x = (ox + d * dx) * 2.0f;
    const float y = (oy + d * dy) * 2.0f;
    const float z = (oz + d * dz) * 2.0f;

    float fx[32];
    #pragma unroll
    for (int c = 0; c < 32; c++) fx[c] = 0.f;

    #pragma unroll
    for (int p = 0; p < 3; p++) {
        const float u = (p == 0) ? x : ((p == 1) ? y : x);
        const float v = (p == 0) ? y : z;
        const float ixf = fmaf(u, 127.5f, 127.5f);
        const float iyf = fmaf(v, 127.5f, 127.5f);
        const float ix0f = floorf(ixf), iy0f = floorf(iyf);
        const float wx1 = ixf - ix0f, wy1 = iyf - iy0f;
        const float wx0 = 1.f - wx1,  wy0 = 1.f - wy1;
        const int ix0 = iclamp((int)ix0f, 0, 255);
        const int ix1 = iclamp((int)ix0f + 1, 0, 255);
        const int iy0 = iclamp((int)iy0f, 0, 255);
        const int iy1 = iclamp((int)iy0f + 1, 0, 255);
        const float wnw = wx0 * wy0, wne = wx1 * wy0, wsw = wx0 * wy1, wse = wx1 * wy1;
        const int i00 = iy0 * WW + ix0, i01 = iy0 * WW + ix1;
        const int i10 = iy1 * WW + ix0, i11 = iy1 * WW + ix1;
        const size_t pb = (size_t)(n * 3 + p) * CC * HH * WW;
        #pragma unroll
        for (int c = 0; c < 32; c++) {
            const size_t cb = pb + (size_t)c * (HH * WW);
            fx[c] += wnw * ldv<F32>(vol, cb + i00) + wne * ldv<F32>(vol, cb + i01)
                   + wsw * ldv<F32>(vol, cb + i10) + wse * ldv<F32>(vol, cb + i11);
        }
    }
    #pragma unroll
    for (int c = 0; c < 32; c++) fx[c] *= (1.0f / 3.0f);

    const float* W1 = wsm;
    const float* B1 = wsm + 2048;
    const float* W2 = wsm + 2112;
    const float* B2 = wsm + 4224;

    float h[64];
    #pragma unroll
    for (int j = 0; j < 64; j++) h[j] = B1[j];
    #pragma unroll
    for (int c = 0; c < 32; c++) {
        const float f = fx[c];
        #pragma unroll
        for (int j = 0; j < 64; j++) h[j] = fmaf(f, W1[c * 64 + j], h[j]);
    }
    #pragma unroll
    for (int j = 0; j < 64; j++) h[j] = softplus_f(h[j]);

    #pragma unroll 1
    for (int k = 0; k < 33; k++) {
        float zz = B2[k];
        #pragma unroll
        for (int j = 0; j < 64; j++) zz = fmaf(h[j], W2[j * 33 + k], zz);
        if (k == 0) sigL[rl][s] = zz;
        else {
            const float sg = 1.0f / (1.0f + expf(-zz));
            rgbL[rl][s][k - 1] = fmaf(sg, 1.002f, -0.001f);
        }
    }
    __syncthreads();

    const int c = t & 31;
    const float delta = 1.05f / 32.0f;
    float T = 1.0f, acc = 0.0f;
    float sig_prev = sigL[rl][0];
    float rgb_prev = rgbL[rl][0][c];
    #pragma unroll 1
    for (int sm = 0; sm < 31; sm++) {
        const float sig_next = sigL[rl][sm + 1];
        const float rgb_next = rgbL[rl][sm + 1][c];
        const float dens = softplus_f(0.5f * (sig_prev + sig_next) - 1.0f);
        const float alpha = 1.0f - expf(-delta * dens);
        acc += alpha * T * 0.5f * (rgb_prev + rgb_next);
        T *= (1.0f - alpha + 1e-10f);
        sig_prev = sig_next;
        rgb_prev = rgb_next;
    }
    const size_t oidx = (size_t)gray * 32 + c;
    if (F32) ((float*)outp)[oidx] = acc;
    else     ((unsigned short*)outp)[oidx] = f2bf_cvt(acc);
}

__global__ __launch_bounds__(256) void render_any(
    const void* __restrict__ vol, const void* __restrict__ rayo,
    const void* __restrict__ rayd, const void* __restrict__ w1b,
    const void* __restrict__ b1b, const void* __restrict__ w2b,
    const void* __restrict__ b2b, void* __restrict__ outp)
{
    __shared__ float wsm[4257];
    __shared__ float rgbL[RPB][SS][33];
    __shared__ float sigL[RPB][SS];
    __shared__ int sflag;
    if (threadIdx.x == 0) sflag = detect_f32_local(rayo);
    __syncthreads();
    const int f32flag = sflag;
    __syncthreads();
    if (f32flag) render_body<true >(vol, rayo, rayd, w1b, b1b, w2b, b2b, outp, wsm, rgbL, sigL);
    else         render_body<false>(vol, rayo, rayd, w1b, b1b, w2b, b2b, outp, wsm, rgbL, sigL);
}

extern "C" void kernel_launch(void* const* d_in, const int* in_sizes, int n_in,
                              void* d_out, int out_size, void* d_ws, size_t ws_size,
                              hipStream_t stream) {
    const void* vol  = d_in[0];
    const void* rayo = d_in[1];
    const void* rayd = d_in[2];
    const void* w1   = d_in[3];
    const void* b1   = d_in[4];
    const void* w2   = d_in[5];
    const void* b2   = d_in[6];
    unsigned short* tex = (unsigned short*)((char*)d_ws + TEXOFF);

    const size_t need = TEXOFF + TEXBYTES;   // bf16 texture always

    if (ws_size >= need) {
        transpose_tex<<<dim3(8 * HH, 6), dim3(256), 0, stream>>>(vol, tex, rayo);
        render_fast<<<dim3(NRAYS / RPB), dim3(256), 0, stream>>>(
            tex, rayo, rayd, w1, b1, w2, b2, d_out);
    } else {
        render_any<<<dim3(NRAYS / RPB), dim3(256), 0, stream>>>(
            vol, rayo, rayd, w1, b1, w2, b2, d_out);
    }
}